// Round 11
// baseline (84.017 us; speedup 1.0000x reference)
//
#include <hip/hip_runtime.h>
#include <math.h>

#define BB 4
#define NN 4096
#define MM 512
#define MH (MM / 2)            // triangles per block (split-m, R10-proven merge)
#define NPT 8                  // points per thread = 4 packed float2 groups
#define TPB 512
#define MCHUNK 4               // i in [0,4): lj = i*64 + ch
#define NPTS_TOT (BB * NN)     // 16384 points

typedef float v2 __attribute__((ext_vector_type(2)));
struct __align__(16) Rec { v2 a, b; };

// ---- guaranteed VOP3P packed fp32 (plain encodings only) ----
__device__ __forceinline__ v2 pk_fma(v2 a, v2 b, v2 c) {
    v2 d; asm("v_pk_fma_f32 %0, %1, %2, %3" : "=v"(d) : "v"(a), "v"(b), "v"(c)); return d;
}
__device__ __forceinline__ v2 pk_mul(v2 a, v2 b) {
    v2 d; asm("v_pk_mul_f32 %0, %1, %2" : "=v"(d) : "v"(a), "v"(b)); return d;
}
__device__ __forceinline__ v2 pk_add(v2 a, v2 b) {
    v2 d; asm("v_pk_add_f32 %0, %1, %2" : "=v"(d) : "v"(a), "v"(b)); return d;
}

// reference _safe_div guard + hw rcp (~1 ulp) -- relative-class error, argmin-safe (R4-R10 validated)
__device__ __forceinline__ float safercp(float y) {
    float yy = (fabsf(y) < 1e-12f) ? 1.0f : y;
    return __builtin_amdgcn_rcpf(yy);
}

// exact IEEE version for phase-2 (matches reference bit-order, validated R1/R3/R6-R10)
__device__ __forceinline__ float safediv(float x, float y) {
    float yy = (fabsf(y) < 1e-12f) ? 1.0f : y;
    return x / yy;
}

__device__ __forceinline__ float clip01s(float x) {
    return fminf(fmaxf(x, 0.0f), 1.0f);   // v_med3_f32
}

// Phase 2: exact reference-ordered Ericson for ONE pair (R1-validated numerics).
__device__ void exact_pair(float px, float py, float pz,
                           float ax, float ay, float az,
                           float bx, float by, float bz,
                           float cx, float cy, float cz,
                           float* dist2_out, int* reg_out) {
#pragma clang fp contract(off)
    const float abx = bx-ax, aby = by-ay, abz = bz-az;
    const float acx = cx-ax, acy = cy-ay, acz = cz-az;
    const float cbx = cx-bx, cby = cy-by, cbz = cz-bz;
    const float apx = px-ax, apy = py-ay, apz = pz-az;
    const float bpx = px-bx, bpy = py-by, bpz = pz-bz;
    const float cpx = px-cx, cpy = py-cy, cpz = pz-cz;

    const float d1 = abx*apx + aby*apy + abz*apz;
    const float d2 = acx*apx + acy*apy + acz*apz;
    const float d3 = abx*bpx + aby*bpy + abz*bpz;
    const float d4 = acx*bpx + acy*bpy + acz*bpz;
    const float d5 = abx*cpx + aby*cpy + abz*cpz;
    const float d6 = acx*cpx + acy*cpy + acz*cpz;

    const float vc = d1*d4 - d3*d2;
    const float vb = d5*d2 - d1*d6;
    const float va = d3*d6 - d5*d4;

    const float v_ab = clip01s(safediv(d1, d1 - d3));
    const float v_ac = clip01s(safediv(d2, d2 - d6));
    const float t43 = d4 - d3;
    const float t56 = d5 - d6;
    const float v_bc = clip01s(safediv(t43, t43 + t56));
    const float denom = va + vb + vc;
    const float v_f = safediv(vb, denom);
    const float w_f = safediv(vc, denom);

    float qx = ax + v_f*abx + w_f*acx;
    float qy = ay + v_f*aby + w_f*acy;
    float qz = az + v_f*abz + w_f*acz;
    int reg = 6;
    const bool c_bc = (va <= 0.0f) && (t43 >= 0.0f) && (t56 >= 0.0f);
    if (c_bc) { qx = bx + v_bc*cbx; qy = by + v_bc*cby; qz = bz + v_bc*cbz; reg = 5; }
    const bool c_ac = (vb <= 0.0f) && (d2 >= 0.0f) && (d6 <= 0.0f);
    if (c_ac) { qx = ax + v_ac*acx; qy = ay + v_ac*acy; qz = az + v_ac*acz; reg = 4; }
    const bool c_c = (d6 >= 0.0f) && (d5 <= d6);
    if (c_c) { qx = cx; qy = cy; qz = cz; reg = 2; }
    const bool c_ab = (vc <= 0.0f) && (d1 >= 0.0f) && (d3 <= 0.0f);
    if (c_ab) { qx = ax + v_ab*abx; qy = ay + v_ab*aby; qz = az + v_ab*abz; reg = 3; }
    const bool c_b = (d3 >= 0.0f) && (d4 <= d3);
    if (c_b) { qx = bx; qy = by; qz = bz; reg = 1; }
    const bool c_a = (d1 <= 0.0f) && (d2 <= 0.0f);
    if (c_a) { qx = ax; qy = ay; qz = az; reg = 0; }

    const float dx = px - qx;
    const float dy = py - qy;
    const float dz = pz - qz;
    *dist2_out = dx*dx + dy*dy + dz*dz;
    *reg_out = reg;
}

// ---- phase-1 kernel: packed min-form distance, key-based argmin ----
__global__ __launch_bounds__(TPB) void tridist_p1(
    const float* __restrict__ xyz1, const float* __restrict__ tri1,
    const float* __restrict__ tri2, const float* __restrict__ tri3,
    float* __restrict__ wd, int* __restrict__ wj)
{
    // Record = 12 data float4 (each holds 2 DUPLICATED v2 constants) + 1 pad
    // float4 -> stride 13 float4 = 208 B. Wave reads 8 CONSECUTIVE records
    // (lj = i*64 + ch); record r starts on bank 20r mod 32 -> all 8 distinct,
    // 8-lane broadcast each -> conflict-free. Duplication makes every
    // ds_read_b128 land as 2 ready v2 operands (zero broadcast movs).
    __shared__ float4 sT[MH * 13];            // 53248 B
    __shared__ float  sPd[NPT][8][8];         // [np][wave][pt] 2 KB
    __shared__ int    sPj[NPT][8][8];         // 2 KB -> total 57344 B

    const int t    = threadIdx.x;
    const int half = blockIdx.x & 1;
    const int bp   = blockIdx.x >> 1;        // [0, 256)
    const int b    = bp >> 6;                // 64 point-blocks per batch
    const int pb   = bp & 63;
    const int pt   = t & 7;
    const int ch   = t >> 3;                 // [0, 64)
    const int jbase = half * MH;

    // ---- stage + per-triangle precompute (threads 0..MH-1) ----
    if (t < MH) {
        const int jj = t;
        const float* g1 = tri1 + ((size_t)b * MM + jbase + jj) * 3;
        const float* g2 = tri2 + ((size_t)b * MM + jbase + jj) * 3;
        const float* g3 = tri3 + ((size_t)b * MM + jbase + jj) * 3;
        const float ax = g1[0], ay = g1[1], az = g1[2];
        const float bx = g2[0], by = g2[1], bz = g2[2];
        const float cx = g3[0], cy = g3[1], cz = g3[2];
        const float abx = bx-ax, aby = by-ay, abz = bz-az;
        const float acx = cx-ax, acy = cy-ay, acz = cz-az;
        const float cbx = cx-bx, cby = cy-by, cbz = cz-bz;
        const float aba  = fmaf(abz, az, fmaf(aby, ay, abx*ax));
        const float aca  = fmaf(acz, az, fmaf(acy, ay, acx*ax));
        const float ab2  = fmaf(abz, abz, fmaf(aby, aby, abx*abx));
        const float ac2  = fmaf(acz, acz, fmaf(acy, acy, acx*acx));
        const float cb2  = fmaf(cbz, cbz, fmaf(cby, cby, cbx*cbx));
        const float abac = fmaf(abz, acz, fmaf(aby, acy, abx*acx));
        const float nrx = fmaf(aby, acz, -(abz*acy));
        const float nry = fmaf(abz, acx, -(abx*acz));
        const float nrz = fmaf(abx, acy, -(aby*acx));
        const float n2  = fmaf(nrz, nrz, fmaf(nry, nry, nrx*nrx));
        const float rn  = __builtin_amdgcn_rsqf(fmaxf(n2, 1e-30f));
        const float nx = nrx*rn, ny = nry*rn, nz = nrz*rn;
        const float nna = -fmaf(nz, az, fmaf(ny, ay, nx*ax));
        const float rab2 = safercp(ab2), rac2 = safercp(ac2), rcb2 = safercp(cb2);
        const int r13 = jj * 13;
        sT[r13 + 0]  = make_float4(abx, abx, aby, aby);
        sT[r13 + 1]  = make_float4(abz, abz, -aba, -aba);
        sT[r13 + 2]  = make_float4(acx, acx, acy, acy);
        sT[r13 + 3]  = make_float4(acz, acz, -aca, -aca);
        sT[r13 + 4]  = make_float4(nx, nx, ny, ny);
        sT[r13 + 5]  = make_float4(nz, nz, nna, nna);
        sT[r13 + 6]  = make_float4(-ab2, -ab2, -abac, -abac);
        sT[r13 + 7]  = make_float4(-ac2, -ac2, rab2, rab2);
        sT[r13 + 8]  = make_float4(rac2, rac2, rcb2, rcb2);
        sT[r13 + 9]  = make_float4(-ax, -ax, -ay, -ay);
        sT[r13 + 10] = make_float4(-az, -az, -cbx, -cbx);
        sT[r13 + 11] = make_float4(-cby, -cby, -cbz, -cbz);
    }
    __syncthreads();

    // ---- 8 points per thread, packed as 4 x float2 ----
    v2 X[4], Y[4], Z[4];
#pragma unroll
    for (int np = 0; np < NPT; ++np) {
        const int gi = b * NN + pb * 64 + np * 8 + pt;
        X[np >> 1][np & 1] = xyz1[gi*3 + 0];
        Y[np >> 1][np & 1] = xyz1[gi*3 + 1];
        Z[np >> 1][np & 1] = xyz1[gi*3 + 2];
    }

    const v2 NEG1 = {-1.0f, -1.0f};
    unsigned int bk[NPT];
#pragma unroll
    for (int np = 0; np < NPT; ++np) bk[np] = 0xFFFFFFFFu;

    const char* base0 = (const char*)sT + ch * 208;   // record ch

#pragma unroll
    for (int i = 0; i < MCHUNK; ++i) {
        const Rec* rp = (const Rec*)(base0 + i * 13312);   // record i*64 + ch
        const Rec q0 = rp[0], q1 = rp[1], q2 = rp[2],  q3 = rp[3];
        const Rec q4 = rp[4], q5 = rp[5], q6 = rp[6],  q7 = rp[7];
        const Rec q8 = rp[8], q9 = rp[9], q10 = rp[10], q11 = rp[11];
        const v2 ABx = q0.a,  ABy = q0.b,  ABz = q1.a,  NABA = q1.b;
        const v2 ACx = q2.a,  ACy = q2.b,  ACz = q3.a,  NACA = q3.b;
        const v2 Nx  = q4.a,  Ny  = q4.b,  Nz  = q5.a,  NNA  = q5.b;
        const v2 NAB2 = q6.a, NABAC = q6.b, NAC2 = q7.a, RAB2 = q7.b;
        const v2 RAC2 = q8.a, RCB2 = q8.b;
        const v2 NAx = q9.a,  NAy = q9.b,  NAz = q10.a;
        const v2 NCBx = q10.b, NCBy = q11.a, NCBz = q11.b;

#pragma unroll
        for (int g = 0; g < 4; ++g) {
            const v2 Xg = X[g], Yg = Y[g], Zg = Z[g];

            const v2 d1 = pk_fma(ABz, Zg, pk_fma(ABy, Yg, pk_fma(ABx, Xg, NABA)));
            const v2 d2 = pk_fma(ACz, Zg, pk_fma(ACy, Yg, pk_fma(ACx, Xg, NACA)));
            const v2 h  = pk_fma(Nz,  Zg, pk_fma(Ny,  Yg, pk_fma(Nx,  Xg, NNA)));
            const v2 d3 = pk_add(d1, NAB2);    // d1 - ab2
            const v2 d4 = pk_add(d2, NABAC);   // d2 - abac
            const v2 d5 = pk_add(d1, NABAC);
            const v2 d6 = pk_add(d2, NAC2);

            const v2 vc = pk_fma(pk_mul(d3, d2), NEG1, pk_mul(d1, d4));
            const v2 vb = pk_fma(pk_mul(d1, d6), NEG1, pk_mul(d5, d2));
            const v2 va = pk_fma(pk_mul(d5, d4), NEG1, pk_mul(d3, d6));
            const v2 t43 = pk_fma(d3, NEG1, d4);

            const v2 uab = pk_mul(d1, RAB2);
            const v2 uac = pk_mul(d2, RAC2);
            const v2 ubc = pk_mul(t43, RCB2);
            v2 vab; vab.x = clip01s(uab.x); vab.y = clip01s(uab.y);
            v2 vac; vac.x = clip01s(uac.x); vac.y = clip01s(uac.y);
            v2 vbc; vbc.x = clip01s(ubc.x); vbc.y = clip01s(ubc.y);

            const v2 apx = pk_add(Xg, NAx);
            const v2 apy = pk_add(Yg, NAy);
            const v2 apz = pk_add(Zg, NAz);
            const v2 bpx = pk_fma(ABx, NEG1, apx);
            const v2 bpy = pk_fma(ABy, NEG1, apy);
            const v2 bpz = pk_fma(ABz, NEG1, apz);

            v2 ex = pk_fma(pk_mul(vab, ABx), NEG1, apx);
            v2 ey = pk_fma(pk_mul(vab, ABy), NEG1, apy);
            v2 ez = pk_fma(pk_mul(vab, ABz), NEG1, apz);
            const v2 dAB = pk_fma(ez, ez, pk_fma(ey, ey, pk_mul(ex, ex)));
            ex = pk_fma(pk_mul(vac, ACx), NEG1, apx);
            ey = pk_fma(pk_mul(vac, ACy), NEG1, apy);
            ez = pk_fma(pk_mul(vac, ACz), NEG1, apz);
            const v2 dAC = pk_fma(ez, ez, pk_fma(ey, ey, pk_mul(ex, ex)));
            ex = pk_fma(vbc, NCBx, bpx);       // bp - ubc*cb (NCB pre-negated)
            ey = pk_fma(vbc, NCBy, bpy);
            ez = pk_fma(vbc, NCBz, bpz);
            const v2 dBC = pk_fma(ez, ez, pk_fma(ey, ey, pk_mul(ex, ex)));
            const v2 dF = pk_mul(h, h);

#pragma unroll
            for (int c = 0; c < 2; ++c) {
                const float mv = fminf(fminf(va[c], vb[c]), vc[c]);
                const float ds = fminf(fminf(dAB[c], dAC[c]), dBC[c]);
                const float dd = (mv >= 0.0f) ? dF[c] : ds;
                // key: dist bits (low 2 masked, 2^-22 rel << 1e-5 noise floor) | i.
                // ascending i -> ascending key on masked ties = first occurrence.
                const unsigned int key = (__float_as_uint(dd) & 0xFFFFFFFCu) | (unsigned int)i;
                const int np = g * 2 + c;
                bk[np] = min(bk[np], key);     // v_min_u32
            }
        }
    }

    // ---- decode keys, butterfly over the 8 chunk-lanes sharing this pt ----
    float bd[NPT]; int bj[NPT];
#pragma unroll
    for (int np = 0; np < NPT; ++np) {
        const unsigned int k = bk[np];
        bd[np] = __uint_as_float(k & 0xFFFFFFFCu);
        bj[np] = jbase + (int)(k & 3u) * 64 + ch;
        for (int off = 8; off <= 32; off <<= 1) {
            const float od = __shfl_xor(bd[np], off, 64);
            const int   oj = __shfl_xor(bj[np], off, 64);
            if (od < bd[np] || (od == bd[np] && oj < bj[np])) {
                bd[np] = od; bj[np] = oj;
            }
        }
    }
    const int lane = t & 63;
    const int w    = t >> 6;                 // wave [0,8)
    if (lane < 8) {
#pragma unroll
        for (int np = 0; np < NPT; ++np) {
            sPd[np][w][lane] = bd[np];
            sPj[np][w][lane] = bj[np];
        }
    }
    __syncthreads();

    if (t < 64) {
        const int np = t >> 3;
        const int p  = t & 7;
        float fbd = INFINITY; int fbj = 0;
        for (int k = 0; k < 8; ++k) {
            const float dk = sPd[np][k][p];
            const int   jk = sPj[np][k][p];
            if (dk < fbd || (dk == fbd && jk < fbj)) { fbd = dk; fbj = jk; }
        }
        const int gidx = b * NN + pb * 64 + np * 8 + p;
        wd[half * NPTS_TOT + gidx] = fbd;
        wj[half * NPTS_TOT + gidx] = fbj;
    }
}

// ---- phase-2 kernel: merge halves, exact recompute, write outputs ----
__global__ __launch_bounds__(256) void tridist_p2(
    const float* __restrict__ xyz1, const float* __restrict__ tri1,
    const float* __restrict__ tri2, const float* __restrict__ tri3,
    const float* __restrict__ wd, const int* __restrict__ wj,
    float* __restrict__ out)
{
    const int gidx = blockIdx.x * 256 + threadIdx.x;   // [0, 16384)
    const float d0 = wd[gidx];
    const float d1 = wd[NPTS_TOT + gidx];
    const int   j0 = wj[gidx];
    const int   j1 = wj[NPTS_TOT + gidx];
    // half0's j are all < half1's j, so strict < gives np.argmin first-occurrence.
    const int bj = (d1 < d0) ? j1 : j0;

    const int b = gidx >> 12;                // 4096 points per batch
    const float* g1 = tri1 + ((size_t)b * MM + bj) * 3;
    const float* g2 = tri2 + ((size_t)b * MM + bj) * 3;
    const float* g3 = tri3 + ((size_t)b * MM + bj) * 3;
    float dist2; int reg;
    exact_pair(xyz1[gidx*3+0], xyz1[gidx*3+1], xyz1[gidx*3+2],
               g1[0], g1[1], g1[2],
               g2[0], g2[1], g2[2],
               g3[0], g3[1], g3[2],
               &dist2, &reg);
    out[gidx]               = dist2;
    out[NPTS_TOT + gidx]    = (float)reg;
    out[2*NPTS_TOT + gidx]  = (float)bj;
}

extern "C" void kernel_launch(void* const* d_in, const int* in_sizes, int n_in,
                              void* d_out, int out_size, void* d_ws, size_t ws_size,
                              hipStream_t stream) {
    const float* xyz1 = (const float*)d_in[0];
    const float* tri1 = (const float*)d_in[1];
    const float* tri2 = (const float*)d_in[2];
    const float* tri3 = (const float*)d_in[3];
    float* out = (float*)d_out;

    float* wd = (float*)d_ws;                        // 2 * 16384 floats
    int*   wj = (int*)((char*)d_ws + 2 * NPTS_TOT * sizeof(float));

    dim3 grid1(BB * (NN / 64) * 2);   // 512 blocks (64 points/block, 2 m-halves)
    tridist_p1<<<grid1, TPB, 0, stream>>>(xyz1, tri1, tri2, tri3, wd, wj);

    dim3 grid2(NPTS_TOT / 256);       // 64 blocks
    tridist_p2<<<grid2, 256, 0, stream>>>(xyz1, tri1, tri2, tri3, wd, wj, out);
}

// Round 12
// 72.670 us; speedup vs baseline: 1.1561x; 1.1561x over previous
//
#include <hip/hip_runtime.h>
#include <math.h>

#define BB 4
#define NN 4096
#define MM 512
#define TPB 512                // thread t owns triangle t
#define PPB 32                 // points per block
#define NPTS_TOT (BB * NN)

// reference _safe_div guard + hw rcp (~1 ulp) -- relative-class error, argmin-safe (R4-R10 validated)
__device__ __forceinline__ float safercp(float y) {
    float yy = (fabsf(y) < 1e-12f) ? 1.0f : y;
    return __builtin_amdgcn_rcpf(yy);
}

// exact IEEE version for phase-2 (matches reference bit-order, validated R1/R3/R6-R10)
__device__ __forceinline__ float safediv(float x, float y) {
    float yy = (fabsf(y) < 1e-12f) ? 1.0f : y;
    return x / yy;
}

__device__ __forceinline__ float clip01s(float x) {
    return fminf(fmaxf(x, 0.0f), 1.0f);   // v_med3_f32
}

// Phase 2: exact reference-ordered Ericson for ONE pair (R1-validated numerics).
__device__ void exact_pair(float px, float py, float pz,
                           float ax, float ay, float az,
                           float bx, float by, float bz,
                           float cx, float cy, float cz,
                           float* dist2_out, int* reg_out) {
#pragma clang fp contract(off)
    const float abx = bx-ax, aby = by-ay, abz = bz-az;
    const float acx = cx-ax, acy = cy-ay, acz = cz-az;
    const float cbx = cx-bx, cby = cy-by, cbz = cz-bz;
    const float apx = px-ax, apy = py-ay, apz = pz-az;
    const float bpx = px-bx, bpy = py-by, bpz = pz-bz;
    const float cpx = px-cx, cpy = py-cy, cpz = pz-cz;

    const float d1 = abx*apx + aby*apy + abz*apz;
    const float d2 = acx*apx + acy*apy + acz*apz;
    const float d3 = abx*bpx + aby*bpy + abz*bpz;
    const float d4 = acx*bpx + acy*bpy + acz*bpz;
    const float d5 = abx*cpx + aby*cpy + abz*cpz;
    const float d6 = acx*cpx + acy*cpy + acz*cpz;

    const float vc = d1*d4 - d3*d2;
    const float vb = d5*d2 - d1*d6;
    const float va = d3*d6 - d5*d4;

    const float v_ab = clip01s(safediv(d1, d1 - d3));
    const float v_ac = clip01s(safediv(d2, d2 - d6));
    const float t43 = d4 - d3;
    const float t56 = d5 - d6;
    const float v_bc = clip01s(safediv(t43, t43 + t56));
    const float denom = va + vb + vc;
    const float v_f = safediv(vb, denom);
    const float w_f = safediv(vc, denom);

    float qx = ax + v_f*abx + w_f*acx;
    float qy = ay + v_f*aby + w_f*acy;
    float qz = az + v_f*abz + w_f*acz;
    int reg = 6;
    const bool c_bc = (va <= 0.0f) && (t43 >= 0.0f) && (t56 >= 0.0f);
    if (c_bc) { qx = bx + v_bc*cbx; qy = by + v_bc*cby; qz = bz + v_bc*cbz; reg = 5; }
    const bool c_ac = (vb <= 0.0f) && (d2 >= 0.0f) && (d6 <= 0.0f);
    if (c_ac) { qx = ax + v_ac*acx; qy = ay + v_ac*acy; qz = az + v_ac*acz; reg = 4; }
    const bool c_c = (d6 >= 0.0f) && (d5 <= d6);
    if (c_c) { qx = cx; qy = cy; qz = cz; reg = 2; }
    const bool c_ab = (vc <= 0.0f) && (d1 >= 0.0f) && (d3 <= 0.0f);
    if (c_ab) { qx = ax + v_ab*abx; qy = ay + v_ab*aby; qz = az + v_ab*abz; reg = 3; }
    const bool c_b = (d3 >= 0.0f) && (d4 <= d3);
    if (c_b) { qx = bx; qy = by; qz = bz; reg = 1; }
    const bool c_a = (d1 <= 0.0f) && (d2 <= 0.0f);
    if (c_a) { qx = ax; qy = ay; qz = az; reg = 0; }

    const float dx = px - qx;
    const float dy = py - qy;
    const float dz = pz - qz;
    *dist2_out = dx*dx + dy*dy + dz*dz;
    *reg_out = reg;
}

__global__ __launch_bounds__(TPB) void tridist_kernel(
    const float* __restrict__ xyz1, const float* __restrict__ tri1,
    const float* __restrict__ tri2, const float* __restrict__ tri3,
    float* __restrict__ out)
{
    // Only LDS: per-(wave, point-lane) packed keys for the cross-wave merge.
    __shared__ unsigned int sK[8][64];        // 2 KB

    const int t    = threadIdx.x;
    const int lane = t & 63;
    const int w    = t >> 6;                 // wave [0,8); wave w owns tris [64w, 64w+64)
    const int b    = blockIdx.x >> 7;        // 128 point-blocks per batch
    const int pb   = blockIdx.x & 127;

    // ---- per-thread triangle constants in registers (j == t), no LDS ----
    const int j = t;
    const float* g1 = tri1 + ((size_t)b * MM + j) * 3;
    const float* g2 = tri2 + ((size_t)b * MM + j) * 3;
    const float* g3 = tri3 + ((size_t)b * MM + j) * 3;
    const float ax = g1[0], ay = g1[1], az = g1[2];
    const float bx = g2[0], by = g2[1], bz = g2[2];
    const float cx = g3[0], cy = g3[1], cz = g3[2];
    const float abx = bx-ax, aby = by-ay, abz = bz-az;
    const float acx = cx-ax, acy = cy-ay, acz = cz-az;
    const float cbx = cx-bx, cby = cy-by, cbz = cz-bz;
    const float naba  = -fmaf(abz, az, fmaf(aby, ay, abx*ax));     // -ab.a
    const float naca  = -fmaf(acz, az, fmaf(acy, ay, acx*ax));     // -ac.a
    const float ab2   = fmaf(abz, abz, fmaf(aby, aby, abx*abx));   // == d1-d3
    const float ac2   = fmaf(acz, acz, fmaf(acy, acy, acx*acx));   // == d2-d6
    const float cb2   = fmaf(cbz, cbz, fmaf(cby, cby, cbx*cbx));
    const float abac  = fmaf(abz, acz, fmaf(aby, acy, abx*acx));
    const float nab2  = -ab2, nabac = -abac, nac2 = -ac2;
    const float rab2  = safercp(ab2), rac2 = safercp(ac2), rcb2 = safercp(cb2);
    const float nrx = fmaf(aby, acz, -(abz*acy));
    const float nry = fmaf(abz, acx, -(abx*acz));
    const float nrz = fmaf(abx, acy, -(aby*acx));
    const float n2  = fmaf(nrz, nrz, fmaf(nry, nry, nrx*nrx));
    const float rn  = __builtin_amdgcn_rsqf(fmaxf(n2, 1e-30f));
    const float nx = nrx*rn, ny = nry*rn, nz = nrz*rn;
    const float nna = -fmaf(nz, az, fmaf(ny, ay, nx*ax));          // -n.a

    // ---- points: wave-uniform loads (SGPR) ----
    const float* pxyz = xyz1 + ((size_t)b * NN + pb * PPB) * 3;

    unsigned int kmine = 0xFFFFFFFFu;        // lane l keeps point l's merged key

#pragma unroll 8
    for (int i = 0; i < PPB; ++i) {
        const float px = pxyz[3*i + 0];      // uniform -> s_load
        const float py = pxyz[3*i + 1];
        const float pz = pxyz[3*i + 2];

        const float d1 = fmaf(abz, pz, fmaf(aby, py, fmaf(abx, px, naba)));
        const float d2 = fmaf(acz, pz, fmaf(acy, py, fmaf(acx, px, naca)));
        const float h  = fmaf(nz,  pz, fmaf(ny,  py, fmaf(nx,  px, nna)));
        const float d3 = d1 + nab2;          // d1 - ab2
        const float d4 = d2 + nabac;         // d2 - abac
        const float d5 = d1 + nabac;
        const float d6 = d2 + nac2;

        const float vc = fmaf(d1, d4, -(d3*d2));
        const float vb = fmaf(d5, d2, -(d1*d6));
        const float va = fmaf(d3, d6, -(d5*d4));
        const float t43 = d4 - d3;

        const float uab = clip01s(d1 * rab2);
        const float uac = clip01s(d2 * rac2);
        const float ubc = clip01s(t43 * rcb2);

        const float apx = px - ax, apy = py - ay, apz = pz - az;
        const float bpx = apx - abx, bpy = apy - aby, bpz = apz - abz;

        float ex = fmaf(-uab, abx, apx), ey = fmaf(-uab, aby, apy), ez = fmaf(-uab, abz, apz);
        const float dAB = fmaf(ez, ez, fmaf(ey, ey, ex*ex));
        ex = fmaf(-uac, acx, apx); ey = fmaf(-uac, acy, apy); ez = fmaf(-uac, acz, apz);
        const float dAC = fmaf(ez, ez, fmaf(ey, ey, ex*ex));
        ex = fmaf(-ubc, cbx, bpx); ey = fmaf(-ubc, cby, bpy); ez = fmaf(-ubc, cbz, bpz);
        const float dBC = fmaf(ez, ez, fmaf(ey, ey, ex*ex));
        const float dF = h * h;

        const float mv   = fminf(fminf(va, vb), vc);          // v_min3
        const float dseg = fminf(fminf(dAB, dAC), dBC);       // v_min3
        const float dd   = (mv >= 0.0f) ? dF : dseg;

        // packed key: dist bits with low 6 masked | lane. 2^-17 (~7.6e-6 rel)
        // quantization — below the validated ~1e-5 phase-1 noise class.
        // Masked ties -> lower lane = lower j = np.argmin first-occurrence.
        unsigned int key = (__float_as_uint(dd) & 0xFFFFFFC0u) | (unsigned int)lane;

        // 6-step butterfly min over the wave's 64 triangles
        key = min(key, (unsigned int)__shfl_xor((int)key, 1, 64));
        key = min(key, (unsigned int)__shfl_xor((int)key, 2, 64));
        key = min(key, (unsigned int)__shfl_xor((int)key, 4, 64));
        key = min(key, (unsigned int)__shfl_xor((int)key, 8, 64));
        key = min(key, (unsigned int)__shfl_xor((int)key, 16, 64));
        key = min(key, (unsigned int)__shfl_xor((int)key, 32, 64));

        if (lane == i) kmine = key;          // lane i archives point i's key
    }

    sK[w][lane] = kmine;
    __syncthreads();

    // ---- cross-wave merge (8 candidates/point) + exact phase-2 ----
    if (t < PPB) {
        float bd = INFINITY; int bj = 0;
        for (int ww = 0; ww < 8; ++ww) {     // ascending ww -> ascending j base
            const unsigned int k = sK[ww][t];
            const float dk = __uint_as_float(k & 0xFFFFFFC0u);
            const int   jk = ww * 64 + (int)(k & 63u);
            if (dk < bd) { bd = dk; bj = jk; }   // strict < keeps first occurrence
        }
        const int gidx = b * NN + pb * PPB + t;
        const float* h1 = tri1 + ((size_t)b * MM + bj) * 3;
        const float* h2 = tri2 + ((size_t)b * MM + bj) * 3;
        const float* h3 = tri3 + ((size_t)b * MM + bj) * 3;
        float dist2; int reg;
        exact_pair(xyz1[gidx*3+0], xyz1[gidx*3+1], xyz1[gidx*3+2],
                   h1[0], h1[1], h1[2],
                   h2[0], h2[1], h2[2],
                   h3[0], h3[1], h3[2],
                   &dist2, &reg);
        out[gidx]               = dist2;
        out[NPTS_TOT + gidx]    = (float)reg;
        out[2*NPTS_TOT + gidx]  = (float)bj;
    }
}

extern "C" void kernel_launch(void* const* d_in, const int* in_sizes, int n_in,
                              void* d_out, int out_size, void* d_ws, size_t ws_size,
                              hipStream_t stream) {
    const float* xyz1 = (const float*)d_in[0];
    const float* tri1 = (const float*)d_in[1];
    const float* tri2 = (const float*)d_in[2];
    const float* tri3 = (const float*)d_in[3];
    float* out = (float*)d_out;

    dim3 grid(BB * (NN / PPB));   // 512 blocks, 32 points x 512 triangles each
    dim3 block(TPB);
    tridist_kernel<<<grid, block, 0, stream>>>(xyz1, tri1, tri2, tri3, out);
}